// Round 1
// baseline (66.297 us; speedup 1.0000x reference)
//
#include <hip/hip_runtime.h>

#define BATCH 16384
#define NGRID 128
#define K 9
#define W 6   // 6x6 candidate window provably contains the true 9-NN on a regular grid

__global__ __launch_bounds__(256) void spline_knn_kernel(
    const float* __restrict__ x,
    const float* __restrict__ wts,
    const float* __restrict__ cp,
    float* __restrict__ out)
{
    int b = blockIdx.x * blockDim.x + threadIdx.x;
    if (b >= BATCH) return;

    float x0 = x[2 * b];
    float x1 = x[2 * b + 1];

    // h = ||x[0] - x[1]|| (data-dependent bandwidth; precision non-critical)
    float e0 = __fadd_rn(x[0], -x[2]);
    float e1 = __fadd_rn(x[1], -x[3]);
    float h = sqrtf(__fadd_rn(__fmul_rn(e0, e0), __fmul_rn(e1, e1)));

    // x2 term exactly as np.sum(x*x, -1): per-op rounding, no contraction
    float x2s = __fadd_rn(__fmul_rn(x0, x0), __fmul_rn(x1, x1));

    // grid position in grid units: p = (x+1) * 127/2
    float pr = (x0 + 1.0f) * 63.5f;
    float pc = (x1 + 1.0f) * 63.5f;
    int r0 = (int)floorf(pr) - 2;
    int c0 = (int)floorf(pc) - 2;
    r0 = min(max(r0, 0), NGRID - W);
    c0 = min(max(c0, 0), NGRID - W);

    // top-9 keys: (monotone-mapped D bits << 32) | flat index
    // smaller key == smaller D, tie -> smaller index (matches jax.lax.top_k)
    unsigned long long best[K];
#pragma unroll
    for (int i = 0; i < K; ++i) best[i] = ~0ULL;

#pragma unroll
    for (int dr = 0; dr < W; ++dr) {
        int row = r0 + dr;
        int mbase = row * NGRID + c0;
        const float* cpr = cp + 2 * mbase;
#pragma unroll
        for (int dc = 0; dc < W; ++dc) {
            float cr = cpr[2 * dc];
            float cc = cpr[2 * dc + 1];
            // replicate np: D = (x2 + c2) - 2.0*(x @ cT), dot via k-ordered FMA
            float c2s = __fadd_rn(__fmul_rn(cr, cr), __fmul_rn(cc, cc));
            float dot = __fmaf_rn(x1, cc, __fmul_rn(x0, cr));
            float D = __fadd_rn(__fadd_rn(x2s, c2s), -__fmul_rn(2.0f, dot));

            unsigned ub = __float_as_uint(D);
            ub ^= ((unsigned)((int)ub >> 31)) | 0x80000000u;  // monotone map for signed floats
            unsigned long long key =
                ((unsigned long long)ub << 32) | (unsigned)(mbase + dc);

            // sorted-insertion network, fully unrolled (no dynamic indexing)
#pragma unroll
            for (int j = 0; j < K; ++j) {
                bool lt = key < best[j];
                unsigned long long lo = lt ? key : best[j];
                unsigned long long hi = lt ? best[j] : key;
                best[j] = lo;
                key = hi;  // evicted max bubbles out
            }
        }
    }

    // epilogue: s = ||x - neighbor|| / h, Keys cubic, weighted sum
    float acc = 0.0f;
#pragma unroll
    for (int j = 0; j < K; ++j) {
        int m = (int)(best[j] & 0xFFFFFFFFull);
        float cr = cp[2 * m];
        float cc = cp[2 * m + 1];
        float dx = x0 - cr;
        float dy = x1 - cc;
        float s = sqrtf(dx * dx + dy * dy) / h;
        float a = fabsf(s);
        float a2 = a * a;
        float a3 = a2 * a;
        float conv;
        if (a < 1.0f)                    conv = 1.5f * a3 - 2.5f * a2 + 1.0f;
        else if (a > 1.0f && a < 2.0f)   conv = -0.5f * a3 + 2.5f * a2 - 4.0f * a + 2.0f;
        else                             conv = 0.0f;   // note: a==1 -> 0, as in reference
        acc += wts[m] * conv;
    }

    out[b] = acc;
    // second tuple output: x passthrough
    out[BATCH + 2 * b]     = x0;
    out[BATCH + 2 * b + 1] = x1;
}

extern "C" void kernel_launch(void* const* d_in, const int* in_sizes, int n_in,
                              void* d_out, int out_size, void* d_ws, size_t ws_size,
                              hipStream_t stream) {
    const float* x  = (const float*)d_in[0];   // (16384, 2) fp32
    const float* w  = (const float*)d_in[1];   // (16384, 1) fp32
    const float* cp = (const float*)d_in[2];   // (16384, 2) fp32
    float* out = (float*)d_out;                // 16384 out + 32768 x passthrough

    spline_knn_kernel<<<BATCH / 256, 256, 0, stream>>>(x, w, cp, out);
}

// Round 3
// 61.311 us; speedup vs baseline: 1.0813x; 1.0813x over previous
//
#include <hip/hip_runtime.h>

#define BATCH 16384
#define NGRID 128
#define K 9
#define W 5   // 5x5 window centered on round(p): provably contains the true 9-NN
              // incl. clamped edges/corners (margins >= 3e-4 in D vs 2.4e-7 fp noise)

__global__ __launch_bounds__(64) void spline_knn_kernel(
    const float* __restrict__ x,
    const float* __restrict__ wts,
    const float* __restrict__ cp,
    float* __restrict__ out)
{
    int b = blockIdx.x * 64 + threadIdx.x;   // grid is exactly BATCH threads

    float2 xv = ((const float2*)x)[b];
    float x0 = xv.x, x1 = xv.y;

    // h = ||x[0] - x[1]|| (precision non-critical)
    float e0 = __fadd_rn(x[0], -x[2]);
    float e1 = __fadd_rn(x[1], -x[3]);
    float h = sqrtf(__fadd_rn(__fmul_rn(e0, e0), __fmul_rn(e1, e1)));

    // x2 term exactly as np.sum(x*x, -1): per-op rounding, no contraction
    float x2s = __fadd_rn(__fmul_rn(x0, x0), __fmul_rn(x1, x1));

    // grid position in grid units: p = (x+1) * 127/2; window centered on ROUND
    float pr = (x0 + 1.0f) * 63.5f;
    float pc = (x1 + 1.0f) * 63.5f;
    int r0 = min(max((int)floorf(pr + 0.5f) - 2, 0), NGRID - W);
    int c0 = min(max((int)floorf(pc + 0.5f) - 2, 0), NGRID - W);

    // regular grid: cp[r*128+c] = (t[r], t[c]) -> separable loads (10 instead of 50)
    float tr[W], tc[W];
#pragma unroll
    for (int i = 0; i < W; ++i) tr[i] = cp[2 * ((r0 + i) * NGRID)];          // t[r0+i]
#pragma unroll
    for (int j = 0; j < W; ++j) tc[j] = cp[2 * (r0 * NGRID + c0 + j) + 1];   // t[c0+j]

    // per-row / per-col partials, rounding identical to the R1-verified kernel:
    //   c2s = fl( fl(cr*cr) + fl(cc*cc) ),  dot = fma(x1, cc, fl(x0*cr))
    float ar[W], br[W], ac[W];
#pragma unroll
    for (int i = 0; i < W; ++i) { ar[i] = __fmul_rn(tr[i], tr[i]); br[i] = __fmul_rn(x0, tr[i]); }
#pragma unroll
    for (int j = 0; j < W; ++j) { ac[j] = __fmul_rn(tc[j], tc[j]); }

    // top-9 keys: (monotone-mapped D bits << 32) | flat index
    // smaller key == smaller D, tie -> smaller index (matches jax.lax.top_k)
    unsigned long long best[K];
#pragma unroll
    for (int i = 0; i < K; ++i) best[i] = ~0ULL;

#pragma unroll
    for (int i = 0; i < W; ++i) {
        int mrow = (r0 + i) * NGRID + c0;
#pragma unroll
        for (int j = 0; j < W; ++j) {
            float c2s = __fadd_rn(ar[i], ac[j]);
            float tmp = __fadd_rn(x2s, c2s);
            float dot = __fmaf_rn(x1, tc[j], br[i]);
            // fma(-2,dot,tmp) == fl(tmp - fl(2*dot)) since 2*dot is exact:
            float D   = __fmaf_rn(-2.0f, dot, tmp);

            unsigned ub = __float_as_uint(D);
            ub ^= ((unsigned)((int)ub >> 31)) | 0x80000000u;  // monotone map
            unsigned long long key =
                ((unsigned long long)ub << 32) | (unsigned)(mrow + j);

            // sorted-insertion network, fully unrolled (no dynamic indexing)
#pragma unroll
            for (int q = 0; q < K; ++q) {
                bool lt = key < best[q];
                unsigned long long lo = lt ? key : best[q];
                unsigned long long hi = lt ? best[q] : key;
                best[q] = lo;
                key = hi;
            }
        }
    }

    // epilogue: decode D from key (s = sqrt(D)/h; ~1e-5 noise vs 0.27 tolerance)
    float invh = 1.0f / h;
    float acc = 0.0f;
#pragma unroll
    for (int q = 0; q < K; ++q) {
        unsigned hi = (unsigned)(best[q] >> 32);
        int m = (int)(best[q] & 0xFFFFFFFFull);
        unsigned mask = ((unsigned)((int)(~hi) >> 31)) | 0x80000000u;  // inverse map
        float D = __uint_as_float(hi ^ mask);
        float s = sqrtf(fmaxf(D, 0.0f)) * invh;
        float a2 = s * s;
        float a3 = a2 * s;
        float conv;
        if (s < 1.0f)                    conv = 1.5f * a3 - 2.5f * a2 + 1.0f;
        else if (s > 1.0f && s < 2.0f)   conv = -0.5f * a3 + 2.5f * a2 - 4.0f * s + 2.0f;
        else                             conv = 0.0f;
        acc += wts[m] * conv;
    }

    out[b] = acc;
    ((float2*)(out + BATCH))[b] = xv;   // second tuple output: x passthrough
}

extern "C" void kernel_launch(void* const* d_in, const int* in_sizes, int n_in,
                              void* d_out, int out_size, void* d_ws, size_t ws_size,
                              hipStream_t stream) {
    const float* x  = (const float*)d_in[0];   // (16384, 2) fp32
    const float* w  = (const float*)d_in[1];   // (16384, 1) fp32
    const float* cp = (const float*)d_in[2];   // (16384, 2) fp32
    float* out = (float*)d_out;                // 16384 out + 32768 x passthrough

    spline_knn_kernel<<<BATCH / 64, 64, 0, stream>>>(x, w, cp, out);
}